// Round 1
// baseline (863.603 us; speedup 1.0000x reference)
//
#include <hip/hip_runtime.h>
#include <math.h>

#define NN 50000
#define FIN 128
#define EE 800000
#define EP 850000            // EE + NN self-loops
#define ETEST 100000
#define NEG_SLOPE 0.2f

static inline int cdiv(long long a, int b) { return (int)((a + b - 1) / b); }

__device__ __forceinline__ void atomicMaxF(float* addr, float val) {
    int* ai = (int*)addr;
    int old = *ai;
    while (val > __int_as_float(old)) {
        int assumed = old;
        old = atomicCAS(ai, assumed, __float_as_int(val));
        if (old == assumed) break;
    }
}

__global__ void init_neginf(float* p, int n) {
    int i = blockIdx.x * 256 + threadIdx.x;
    if (i < n) p[i] = -INFINITY;
}

// x[NN,128] @ W[128,64] -> h[NN,64]; fused per-head attention dots (H=8,C=8)
__global__ void gemm1_kernel(const float* __restrict__ x, const float* __restrict__ W,
                             const float* __restrict__ att_src, const float* __restrict__ att_dst,
                             float* __restrict__ h, float* __restrict__ a_src, float* __restrict__ a_dst) {
    __shared__ float Ws[FIN * 64];
    int tid = threadIdx.x;
    for (int i = tid; i < FIN * 64; i += 256) Ws[i] = W[i];
    __syncthreads();
    int row = blockIdx.x * 4 + (tid >> 6);   // one row per wave
    int col = tid & 63;
    const float* xr = x + (size_t)row * FIN;
    float acc = 0.f;
#pragma unroll 8
    for (int k = 0; k < FIN; ++k) acc = fmaf(xr[k], Ws[k * 64 + col], acc);
    h[(size_t)row * 64 + col] = acc;
    int head = col >> 3, c = col & 7;
    float ps = acc * att_src[head * 8 + c];
    float pd = acc * att_dst[head * 8 + c];
#pragma unroll
    for (int off = 4; off >= 1; off >>= 1) {      // reduce within 8-lane head groups
        ps += __shfl_xor(ps, off, 64);
        pd += __shfl_xor(pd, off, 64);
    }
    if (c == 0) { a_src[row * 8 + head] = ps; a_dst[row * 8 + head] = pd; }
}

// z[NN,64] @ W[64,64] -> h[NN,64]; fused attention dots (H=1,C=64)
__global__ void gemm2_kernel(const float* __restrict__ z, const float* __restrict__ W,
                             const float* __restrict__ att_src, const float* __restrict__ att_dst,
                             float* __restrict__ h, float* __restrict__ a_src, float* __restrict__ a_dst) {
    __shared__ float Ws[64 * 64];
    int tid = threadIdx.x;
    for (int i = tid; i < 64 * 64; i += 256) Ws[i] = W[i];
    __syncthreads();
    int row = blockIdx.x * 4 + (tid >> 6);
    int col = tid & 63;
    const float* zr = z + (size_t)row * 64;
    float acc = 0.f;
#pragma unroll 8
    for (int k = 0; k < 64; ++k) acc = fmaf(zr[k], Ws[k * 64 + col], acc);
    h[(size_t)row * 64 + col] = acc;
    float ps = acc * att_src[col];
    float pd = acc * att_dst[col];
#pragma unroll
    for (int off = 32; off >= 1; off >>= 1) {
        ps += __shfl_xor(ps, off, 64);
        pd += __shfl_xor(pd, off, 64);
    }
    if (col == 0) { a_src[row] = ps; a_dst[row] = pd; }
}

// ---- layer 1 edge passes (H=8). t = e*8 + h ----
__global__ void edge1_alpha_max(const int* __restrict__ ei, const float* __restrict__ a_src,
                                const float* __restrict__ a_dst, float* __restrict__ alpha,
                                float* __restrict__ m) {
    long long t = (long long)blockIdx.x * 256 + threadIdx.x;
    if (t >= (long long)EP * 8) return;
    int e = (int)(t >> 3), h = (int)(t & 7);
    int src, dst;
    if (e < EE) { src = ei[e]; dst = ei[EE + e]; } else { src = dst = e - EE; }
    float a = a_src[src * 8 + h] + a_dst[dst * 8 + h];
    a = a > 0.f ? a : NEG_SLOPE * a;
    alpha[t] = a;
    atomicMaxF(&m[dst * 8 + h], a);
}

__global__ void edge1_exp_sum(const int* __restrict__ ei, const float* __restrict__ m,
                              float* __restrict__ alpha, float* __restrict__ denom) {
    long long t = (long long)blockIdx.x * 256 + threadIdx.x;
    if (t >= (long long)EP * 8) return;
    int e = (int)(t >> 3), h = (int)(t & 7);
    int dst;
    if (e < EE) { dst = ei[EE + e]; } else { dst = e - EE; }
    float ex = expf(alpha[t] - m[dst * 8 + h]);
    alpha[t] = ex;
    atomicAdd(&denom[dst * 8 + h], ex);
}

__global__ void edge1_scatter(const int* __restrict__ ei, const float* __restrict__ alpha,
                              const float* __restrict__ denom, const float* __restrict__ h,
                              float* __restrict__ out) {
    long long t = (long long)blockIdx.x * 256 + threadIdx.x;
    if (t >= (long long)EP * 64) return;
    int e = (int)(t >> 6), c = (int)(t & 63), hd = c >> 3;
    int src, dst;
    if (e < EE) { src = ei[e]; dst = ei[EE + e]; } else { src = dst = e - EE; }
    float coef = alpha[(long long)e * 8 + hd] / fmaxf(denom[dst * 8 + hd], 1e-16f);
    atomicAdd(&out[(size_t)dst * 64 + c], h[(size_t)src * 64 + c] * coef);
}

__global__ void bias_elu(float* __restrict__ z, const float* __restrict__ bias) {
    int i = blockIdx.x * 256 + threadIdx.x;
    if (i < NN * 64) {
        float v = z[i] + bias[i & 63];
        z[i] = v > 0.f ? v : expm1f(v);
    }
}

// ---- layer 2 edge passes (H=1, C=64) ----
__global__ void edge2_alpha_max(const int* __restrict__ ei, const float* __restrict__ a_src,
                                const float* __restrict__ a_dst, float* __restrict__ alpha,
                                float* __restrict__ m) {
    int e = blockIdx.x * 256 + threadIdx.x;
    if (e >= EP) return;
    int src, dst;
    if (e < EE) { src = ei[e]; dst = ei[EE + e]; } else { src = dst = e - EE; }
    float a = a_src[src] + a_dst[dst];
    a = a > 0.f ? a : NEG_SLOPE * a;
    alpha[e] = a;
    atomicMaxF(&m[dst], a);
}

__global__ void edge2_exp_sum(const int* __restrict__ ei, const float* __restrict__ m,
                              float* __restrict__ alpha, float* __restrict__ denom) {
    int e = blockIdx.x * 256 + threadIdx.x;
    if (e >= EP) return;
    int dst;
    if (e < EE) { dst = ei[EE + e]; } else { dst = e - EE; }
    float ex = expf(alpha[e] - m[dst]);
    alpha[e] = ex;
    atomicAdd(&denom[dst], ex);
}

__global__ void edge2_scatter(const int* __restrict__ ei, const float* __restrict__ alpha,
                              const float* __restrict__ denom, const float* __restrict__ h,
                              float* __restrict__ out) {
    long long t = (long long)blockIdx.x * 256 + threadIdx.x;
    if (t >= (long long)EP * 64) return;
    int e = (int)(t >> 6), c = (int)(t & 63);
    int src, dst;
    if (e < EE) { src = ei[e]; dst = ei[EE + e]; } else { src = dst = e - EE; }
    float coef = alpha[e] / fmaxf(denom[dst], 1e-16f);
    atomicAdd(&out[(size_t)dst * 64 + c], h[(size_t)src * 64 + c] * coef);
}

__global__ void bias_add(float* __restrict__ z, const float* __restrict__ bias) {
    int i = blockIdx.x * 256 + threadIdx.x;
    if (i < NN * 64) z[i] += bias[i & 63];
}

// logits[i] = dot64(z2[a], z2[b]); one wave per logit
__global__ void logits_kernel(const int* __restrict__ pos, const int* __restrict__ neg,
                              const float* __restrict__ z2, float* __restrict__ out) {
    long long t = (long long)blockIdx.x * 256 + threadIdx.x;
    if (t >= (long long)2 * ETEST * 64) return;
    int i = (int)(t >> 6), c = (int)(t & 63);
    int a, b;
    if (i < ETEST) { a = pos[i]; b = pos[ETEST + i]; }
    else           { a = neg[i - ETEST]; b = neg[i]; }
    float p = z2[(size_t)a * 64 + c] * z2[(size_t)b * 64 + c];
#pragma unroll
    for (int off = 32; off >= 1; off >>= 1) p += __shfl_xor(p, off, 64);
    if (c == 0) out[i] = p;
}

extern "C" void kernel_launch(void* const* d_in, const int* in_sizes, int n_in,
                              void* d_out, int out_size, void* d_ws, size_t ws_size,
                              hipStream_t stream) {
    const float* x    = (const float*)d_in[0];
    const int*   ei   = (const int*)d_in[1];
    const int*   pos  = (const int*)d_in[2];
    const int*   neg  = (const int*)d_in[3];
    const float* W1   = (const float*)d_in[4];
    const float* asr1 = (const float*)d_in[5];
    const float* ads1 = (const float*)d_in[6];
    const float* b1   = (const float*)d_in[7];
    const float* W2   = (const float*)d_in[8];
    const float* asr2 = (const float*)d_in[9];
    const float* ads2 = (const float*)d_in[10];
    const float* b2   = (const float*)d_in[11];
    float* out = (float*)d_out;

    float* ws  = (float*)d_ws;
    float* h1  = ws;                       // NN*64, reused as h2 after layer 1
    float* z1  = h1 + (size_t)NN * 64;     // NN*64
    float* z2  = z1 + (size_t)NN * 64;     // NN*64
    float* as1 = z2 + (size_t)NN * 64;     // NN*8
    float* ad1 = as1 + (size_t)NN * 8;
    float* m1  = ad1 + (size_t)NN * 8;
    float* d1  = m1 + (size_t)NN * 8;
    float* as2 = d1 + (size_t)NN * 8;      // NN
    float* ad2 = as2 + NN;
    float* m2  = ad2 + NN;
    float* d2  = m2 + NN;
    float* alpha = d2 + NN;                // EP*8 (layer1), first EP reused for layer2
    // total: ~18.2M floats (~73 MB)

    hipMemsetAsync(z1, 0, (size_t)NN * 64 * sizeof(float), stream);
    hipMemsetAsync(z2, 0, (size_t)NN * 64 * sizeof(float), stream);
    hipMemsetAsync(d1, 0, (size_t)NN * 8 * sizeof(float), stream);
    hipMemsetAsync(d2, 0, (size_t)NN * sizeof(float), stream);
    init_neginf<<<cdiv(NN * 8, 256), 256, 0, stream>>>(m1, NN * 8);
    init_neginf<<<cdiv(NN, 256), 256, 0, stream>>>(m2, NN);

    // ---- layer 1 ----
    gemm1_kernel<<<NN / 4, 256, 0, stream>>>(x, W1, asr1, ads1, h1, as1, ad1);
    edge1_alpha_max<<<cdiv((long long)EP * 8, 256), 256, 0, stream>>>(ei, as1, ad1, alpha, m1);
    edge1_exp_sum<<<cdiv((long long)EP * 8, 256), 256, 0, stream>>>(ei, m1, alpha, d1);
    edge1_scatter<<<cdiv((long long)EP * 64, 256), 256, 0, stream>>>(ei, alpha, d1, h1, z1);
    bias_elu<<<cdiv(NN * 64, 256), 256, 0, stream>>>(z1, b1);

    // ---- layer 2 ----
    gemm2_kernel<<<NN / 4, 256, 0, stream>>>(z1, W2, asr2, ads2, h1, as2, ad2);
    edge2_alpha_max<<<cdiv(EP, 256), 256, 0, stream>>>(ei, as2, ad2, alpha, m2);
    edge2_exp_sum<<<cdiv(EP, 256), 256, 0, stream>>>(ei, m2, alpha, d2);
    edge2_scatter<<<cdiv((long long)EP * 64, 256), 256, 0, stream>>>(ei, alpha, d2, h1, z2);
    bias_add<<<cdiv(NN * 64, 256), 256, 0, stream>>>(z2, b2);

    // ---- link-prediction logits ----
    logits_kernel<<<cdiv((long long)2 * ETEST * 64, 256), 256, 0, stream>>>(pos, neg, z2, out);
}

// Round 2
// 695.890 us; speedup vs baseline: 1.2410x; 1.2410x over previous
//
#include <hip/hip_runtime.h>
#include <math.h>

#define NN 50000
#define FIN 128
#define EE 800000
#define EP 850000            // EE + NN self-loops
#define ETEST 100000
#define NEG_SLOPE 0.2f

static inline int cdiv(long long a, int b) { return (int)((a + b - 1) / b); }

// ---------------- CSR build (by dst), rebuilt every call ----------------

__global__ void hist_kernel(const int* __restrict__ ei, int* __restrict__ deg) {
    int e = blockIdx.x * 256 + threadIdx.x;
    if (e >= EP) return;
    int dst = (e < EE) ? ei[EE + e] : (e - EE);
    atomicAdd(&deg[dst], 1);
}

// single-block exclusive scan over deg[NN] -> rowptr[NN+1], cursor[NN]
__global__ void scan_kernel(const int* __restrict__ deg, int* __restrict__ rowptr,
                            int* __restrict__ cursor) {
    __shared__ int part[1024];
    int t = threadIdx.x;
    const int CH = (NN + 1023) / 1024;   // 49
    int base = t * CH;
    int sum = 0;
    for (int i = 0; i < CH; ++i) {
        int idx = base + i;
        if (idx < NN) sum += deg[idx];
    }
    part[t] = sum;
    __syncthreads();
    for (int off = 1; off < 1024; off <<= 1) {
        int v = part[t];
        int u = (t >= off) ? part[t - off] : 0;
        __syncthreads();
        part[t] = v + u;
        __syncthreads();
    }
    int run = (t > 0) ? part[t - 1] : 0;
    for (int i = 0; i < CH; ++i) {
        int idx = base + i;
        if (idx < NN) {
            rowptr[idx] = run;
            cursor[idx] = run;
            run += deg[idx];
        }
    }
    if (t == 1023) rowptr[NN] = EP;
}

__global__ void fill_kernel(const int* __restrict__ ei, int* __restrict__ cursor,
                            int* __restrict__ col) {
    int e = blockIdx.x * 256 + threadIdx.x;
    if (e >= EP) return;
    int src, dst;
    if (e < EE) { src = ei[e]; dst = ei[EE + e]; } else { src = dst = e - EE; }
    int pos = atomicAdd(&cursor[dst], 1);
    col[pos] = src;
}

// ---------------- GEMMs with fused attention dots ----------------

// x[NN,128] @ W[128,64] -> h[NN,64]; per-head dots (H=8,C=8)
__global__ void gemm1_kernel(const float* __restrict__ x, const float* __restrict__ W,
                             const float* __restrict__ att_src, const float* __restrict__ att_dst,
                             float* __restrict__ h, float* __restrict__ a_src, float* __restrict__ a_dst) {
    __shared__ float Ws[FIN * 64];
    int tid = threadIdx.x;
    for (int i = tid; i < FIN * 64; i += 256) Ws[i] = W[i];
    __syncthreads();
    int row = blockIdx.x * 4 + (tid >> 6);   // one row per wave
    int col = tid & 63;
    const float* xr = x + (size_t)row * FIN;
    float acc = 0.f;
#pragma unroll 8
    for (int k = 0; k < FIN; ++k) acc = fmaf(xr[k], Ws[k * 64 + col], acc);
    h[(size_t)row * 64 + col] = acc;
    int head = col >> 3, c = col & 7;
    float ps = acc * att_src[head * 8 + c];
    float pd = acc * att_dst[head * 8 + c];
#pragma unroll
    for (int off = 4; off >= 1; off >>= 1) {   // reduce within 8-lane head groups
        ps += __shfl_xor(ps, off, 64);
        pd += __shfl_xor(pd, off, 64);
    }
    if (c == 0) { a_src[row * 8 + head] = ps; a_dst[row * 8 + head] = pd; }
}

// z[NN,64] @ W[64,64] -> h[NN,64]; dots (H=1,C=64)
__global__ void gemm2_kernel(const float* __restrict__ z, const float* __restrict__ W,
                             const float* __restrict__ att_src, const float* __restrict__ att_dst,
                             float* __restrict__ h, float* __restrict__ a_src, float* __restrict__ a_dst) {
    __shared__ float Ws[64 * 64];
    int tid = threadIdx.x;
    for (int i = tid; i < 64 * 64; i += 256) Ws[i] = W[i];
    __syncthreads();
    int row = blockIdx.x * 4 + (tid >> 6);
    int col = tid & 63;
    const float* zr = z + (size_t)row * 64;
    float acc = 0.f;
#pragma unroll 8
    for (int k = 0; k < 64; ++k) acc = fmaf(zr[k], Ws[k * 64 + col], acc);
    h[(size_t)row * 64 + col] = acc;
    float ps = acc * att_src[col];
    float pd = acc * att_dst[col];
#pragma unroll
    for (int off = 32; off >= 1; off >>= 1) {
        ps += __shfl_xor(ps, off, 64);
        pd += __shfl_xor(pd, off, 64);
    }
    if (col == 0) { a_src[row] = ps; a_dst[row] = pd; }
}

// ---------------- Fused GAT aggregation (gather, no atomics) ----------------

// Layer 1: H=8, C=8. One wave per dst node; lane = h*8+c.
// Pass 1: per-head max (lanes of one head compute identical alpha -> no shuffles).
// Pass 2: denom + weighted message accumulated together; epilogue: /denom + bias, ELU.
__global__ void gat1_gather(const int* __restrict__ rowptr, const int* __restrict__ col,
                            const float* __restrict__ asrc, const float* __restrict__ adst,
                            const float* __restrict__ hfeat, const float* __restrict__ bias,
                            float* __restrict__ z1) {
    int v = blockIdx.x * 4 + (threadIdx.x >> 6);
    if (v >= NN) return;
    int lane = threadIdx.x & 63;
    int h = lane >> 3;
    int beg = rowptr[v], end = rowptr[v + 1];
    float ad = adst[v * 8 + h];
    float m = -INFINITY;
    for (int i = beg; i < end; ++i) {
        int s = col[i];
        float a = asrc[s * 8 + h] + ad;
        a = a > 0.f ? a : NEG_SLOPE * a;
        m = fmaxf(m, a);
    }
    float den = 0.f, acc = 0.f;
    for (int i = beg; i < end; ++i) {
        int s = col[i];
        float a = asrc[s * 8 + h] + ad;
        a = a > 0.f ? a : NEG_SLOPE * a;
        float e = __expf(a - m);
        den += e;
        acc = fmaf(e, hfeat[(size_t)s * 64 + lane], acc);
    }
    float o = acc / fmaxf(den, 1e-16f) + bias[lane];
    z1[(size_t)v * 64 + lane] = o > 0.f ? o : expm1f(o);   // fused ELU
}

// Layer 2: H=1, C=64. Same structure; alpha identical across all 64 lanes.
__global__ void gat2_gather(const int* __restrict__ rowptr, const int* __restrict__ col,
                            const float* __restrict__ asrc, const float* __restrict__ adst,
                            const float* __restrict__ hfeat, const float* __restrict__ bias,
                            float* __restrict__ z2) {
    int v = blockIdx.x * 4 + (threadIdx.x >> 6);
    if (v >= NN) return;
    int lane = threadIdx.x & 63;
    int beg = rowptr[v], end = rowptr[v + 1];
    float ad = adst[v];
    float m = -INFINITY;
    for (int i = beg; i < end; ++i) {
        int s = col[i];
        float a = asrc[s] + ad;
        a = a > 0.f ? a : NEG_SLOPE * a;
        m = fmaxf(m, a);
    }
    float den = 0.f, acc = 0.f;
    for (int i = beg; i < end; ++i) {
        int s = col[i];
        float a = asrc[s] + ad;
        a = a > 0.f ? a : NEG_SLOPE * a;
        float e = __expf(a - m);
        den += e;
        acc = fmaf(e, hfeat[(size_t)s * 64 + lane], acc);
    }
    z2[(size_t)v * 64 + lane] = acc / fmaxf(den, 1e-16f) + bias[lane];
}

// logits[i] = dot64(z2[a], z2[b]); one wave per logit
__global__ void logits_kernel(const int* __restrict__ pos, const int* __restrict__ neg,
                              const float* __restrict__ z2, float* __restrict__ out) {
    long long t = (long long)blockIdx.x * 256 + threadIdx.x;
    if (t >= (long long)2 * ETEST * 64) return;
    int i = (int)(t >> 6), c = (int)(t & 63);
    int a, b;
    if (i < ETEST) { a = pos[i]; b = pos[ETEST + i]; }
    else           { a = neg[i - ETEST]; b = neg[i]; }
    float p = z2[(size_t)a * 64 + c] * z2[(size_t)b * 64 + c];
#pragma unroll
    for (int off = 32; off >= 1; off >>= 1) p += __shfl_xor(p, off, 64);
    if (c == 0) out[i] = p;
}

extern "C" void kernel_launch(void* const* d_in, const int* in_sizes, int n_in,
                              void* d_out, int out_size, void* d_ws, size_t ws_size,
                              hipStream_t stream) {
    const float* x    = (const float*)d_in[0];
    const int*   ei   = (const int*)d_in[1];
    const int*   pos  = (const int*)d_in[2];
    const int*   neg  = (const int*)d_in[3];
    const float* W1   = (const float*)d_in[4];
    const float* asr1 = (const float*)d_in[5];
    const float* ads1 = (const float*)d_in[6];
    const float* b1   = (const float*)d_in[7];
    const float* W2   = (const float*)d_in[8];
    const float* asr2 = (const float*)d_in[9];
    const float* ads2 = (const float*)d_in[10];
    const float* b2   = (const float*)d_in[11];
    float* out = (float*)d_out;

    float* ws  = (float*)d_ws;
    float* h1  = ws;                       // NN*64 (h of layer1, reused as h of layer2)
    float* z1  = h1 + (size_t)NN * 64;     // NN*64
    float* z2  = z1 + (size_t)NN * 64;     // NN*64
    float* as1 = z2 + (size_t)NN * 64;     // NN*8
    float* ad1 = as1 + (size_t)NN * 8;     // NN*8
    float* as2 = ad1 + (size_t)NN * 8;     // NN
    float* ad2 = as2 + NN;                 // NN
    int* deg    = (int*)(ad2 + NN);        // NN
    int* rowptr = deg + NN;                // NN+1
    int* cursor = rowptr + NN + 1;         // NN
    int* csrcol = cursor + NN;             // EP
    // total ≈ 10.3M f32 + 1.0M int ≈ 45 MB

    // ---- CSR build (shared by both layers) ----
    hipMemsetAsync(deg, 0, (size_t)NN * sizeof(int), stream);
    hist_kernel<<<cdiv(EP, 256), 256, 0, stream>>>(ei, deg);
    scan_kernel<<<1, 1024, 0, stream>>>(deg, rowptr, cursor);
    fill_kernel<<<cdiv(EP, 256), 256, 0, stream>>>(ei, cursor, csrcol);

    // ---- layer 1 ----
    gemm1_kernel<<<NN / 4, 256, 0, stream>>>(x, W1, asr1, ads1, h1, as1, ad1);
    gat1_gather<<<cdiv(NN, 4), 256, 0, stream>>>(rowptr, csrcol, as1, ad1, h1, b1, z1);

    // ---- layer 2 ----
    gemm2_kernel<<<NN / 4, 256, 0, stream>>>(z1, W2, asr2, ads2, h1, as2, ad2);
    gat2_gather<<<cdiv(NN, 4), 256, 0, stream>>>(rowptr, csrcol, as2, ad2, h1, b2, z2);

    // ---- link-prediction logits ----
    logits_kernel<<<cdiv((long long)2 * ETEST * 64, 256), 256, 0, stream>>>(pos, neg, z2, out);
}

// Round 3
// 521.939 us; speedup vs baseline: 1.6546x; 1.3333x over previous
//
#include <hip/hip_runtime.h>
#include <math.h>

#define NN 50000
#define FIN 128
#define EE 800000
#define EP 850000            // EE + NN self-loops
#define ETEST 100000
#define NEG_SLOPE 0.2f

static inline int cdiv(long long a, int b) { return (int)((a + b - 1) / b); }

// ---------------- CSR build (by dst), rebuilt every call ----------------

__global__ void hist_kernel(const int* __restrict__ ei, int* __restrict__ deg) {
    int e = blockIdx.x * 256 + threadIdx.x;
    if (e >= EP) return;
    int dst = (e < EE) ? ei[EE + e] : (e - EE);
    atomicAdd(&deg[dst], 1);
}

// single-block exclusive scan over deg[NN] -> rowptr[NN+1], cursor[NN]
__global__ void scan_kernel(const int* __restrict__ deg, int* __restrict__ rowptr,
                            int* __restrict__ cursor) {
    __shared__ int part[1024];
    int t = threadIdx.x;
    const int CH = (NN + 1023) / 1024;   // 49
    int base = t * CH;
    int sum = 0;
    for (int i = 0; i < CH; ++i) {
        int idx = base + i;
        if (idx < NN) sum += deg[idx];
    }
    part[t] = sum;
    __syncthreads();
    for (int off = 1; off < 1024; off <<= 1) {
        int v = part[t];
        int u = (t >= off) ? part[t - off] : 0;
        __syncthreads();
        part[t] = v + u;
        __syncthreads();
    }
    int run = (t > 0) ? part[t - 1] : 0;
    for (int i = 0; i < CH; ++i) {
        int idx = base + i;
        if (idx < NN) {
            rowptr[idx] = run;
            cursor[idx] = run;
            run += deg[idx];
        }
    }
    if (t == 1023) rowptr[NN] = EP;
}

__global__ void fill_kernel(const int* __restrict__ ei, int* __restrict__ cursor,
                            int* __restrict__ col) {
    int e = blockIdx.x * 256 + threadIdx.x;
    if (e >= EP) return;
    int src, dst;
    if (e < EE) { src = ei[e]; dst = ei[EE + e]; } else { src = dst = e - EE; }
    int pos = atomicAdd(&cursor[dst], 1);
    col[pos] = src;
}

// ---------------- GEMMs with fused attention dots (grid-stride rows) ----------------

#define GB1 1250   // blocks for gemm kernels; rows stride = GB1*4 waves

// x[NN,128] @ W[128,64] -> h[NN,64]; per-head dots (H=8,C=8)
__global__ void gemm1_kernel(const float* __restrict__ x, const float* __restrict__ W,
                             const float* __restrict__ att_src, const float* __restrict__ att_dst,
                             float* __restrict__ h, float* __restrict__ a_src, float* __restrict__ a_dst) {
    __shared__ float Ws[FIN * 64];
    int tid = threadIdx.x;
    for (int i = tid; i < FIN * 64; i += 256) Ws[i] = W[i];
    __syncthreads();
    int col = tid & 63;
    int head = col >> 3, c = col & 7;
    float atts = att_src[head * 8 + c];
    float attd = att_dst[head * 8 + c];
    for (int row = blockIdx.x * 4 + (tid >> 6); row < NN; row += GB1 * 4) {
        const float* xr = x + (size_t)row * FIN;
        float acc = 0.f;
#pragma unroll 8
        for (int k = 0; k < FIN; ++k) acc = fmaf(xr[k], Ws[k * 64 + col], acc);
        h[(size_t)row * 64 + col] = acc;
        float ps = acc * atts;
        float pd = acc * attd;
#pragma unroll
        for (int off = 4; off >= 1; off >>= 1) {   // reduce within 8-lane head groups
            ps += __shfl_xor(ps, off, 64);
            pd += __shfl_xor(pd, off, 64);
        }
        if (c == 0) { a_src[row * 8 + head] = ps; a_dst[row * 8 + head] = pd; }
    }
}

// z[NN,64] @ W[64,64] -> h[NN,64]; dots (H=1,C=64)
__global__ void gemm2_kernel(const float* __restrict__ z, const float* __restrict__ W,
                             const float* __restrict__ att_src, const float* __restrict__ att_dst,
                             float* __restrict__ h, float* __restrict__ a_src, float* __restrict__ a_dst) {
    __shared__ float Ws[64 * 64];
    int tid = threadIdx.x;
    for (int i = tid; i < 64 * 64; i += 256) Ws[i] = W[i];
    __syncthreads();
    int col = tid & 63;
    float atts = att_src[col];
    float attd = att_dst[col];
    for (int row = blockIdx.x * 4 + (tid >> 6); row < NN; row += GB1 * 4) {
        const float* zr = z + (size_t)row * 64;
        float acc = 0.f;
#pragma unroll 8
        for (int k = 0; k < 64; ++k) acc = fmaf(zr[k], Ws[k * 64 + col], acc);
        h[(size_t)row * 64 + col] = acc;
        float ps = acc * atts;
        float pd = acc * attd;
#pragma unroll
        for (int off = 32; off >= 1; off >>= 1) {
            ps += __shfl_xor(ps, off, 64);
            pd += __shfl_xor(pd, off, 64);
        }
        if (col == 0) { a_src[row] = ps; a_dst[row] = pd; }
    }
}

// ---------------- Fused GAT aggregation: single pass, no max (cancels), 4x unroll ----------------

__device__ __forceinline__ float lrelu(float a) { return a > 0.f ? a : NEG_SLOPE * a; }

// Layer 1: H=8, C=8. One wave per dst node; lane = h*8+c.
__global__ void gat1_gather(const int* __restrict__ rowptr, const int* __restrict__ col,
                            const float* __restrict__ asrc, const float* __restrict__ adst,
                            const float* __restrict__ hfeat, const float* __restrict__ bias,
                            float* __restrict__ z1) {
    int v = blockIdx.x * 4 + (threadIdx.x >> 6);
    if (v >= NN) return;
    int lane = threadIdx.x & 63;
    int h = lane >> 3;
    int beg = rowptr[v], end = rowptr[v + 1];
    float ad = adst[v * 8 + h];
    float den = 0.f, acc = 0.f;
    int i = beg;
    for (; i + 4 <= end; i += 4) {
        int s0 = col[i], s1 = col[i + 1], s2 = col[i + 2], s3 = col[i + 3];
        float a0 = asrc[s0 * 8 + h] + ad;
        float a1 = asrc[s1 * 8 + h] + ad;
        float a2 = asrc[s2 * 8 + h] + ad;
        float a3 = asrc[s3 * 8 + h] + ad;
        float f0 = hfeat[(size_t)s0 * 64 + lane];
        float f1 = hfeat[(size_t)s1 * 64 + lane];
        float f2 = hfeat[(size_t)s2 * 64 + lane];
        float f3 = hfeat[(size_t)s3 * 64 + lane];
        float e0 = __expf(lrelu(a0));
        float e1 = __expf(lrelu(a1));
        float e2 = __expf(lrelu(a2));
        float e3 = __expf(lrelu(a3));
        den += (e0 + e1) + (e2 + e3);
        acc = fmaf(e0, f0, fmaf(e1, f1, fmaf(e2, f2, fmaf(e3, f3, acc))));
    }
    for (; i < end; ++i) {
        int s = col[i];
        float e = __expf(lrelu(asrc[s * 8 + h] + ad));
        den += e;
        acc = fmaf(e, hfeat[(size_t)s * 64 + lane], acc);
    }
    float o = acc / fmaxf(den, 1e-16f) + bias[lane];
    z1[(size_t)v * 64 + lane] = o > 0.f ? o : expm1f(o);   // fused ELU
}

// Layer 2: H=1, C=64.
__global__ void gat2_gather(const int* __restrict__ rowptr, const int* __restrict__ col,
                            const float* __restrict__ asrc, const float* __restrict__ adst,
                            const float* __restrict__ hfeat, const float* __restrict__ bias,
                            float* __restrict__ z2) {
    int v = blockIdx.x * 4 + (threadIdx.x >> 6);
    if (v >= NN) return;
    int lane = threadIdx.x & 63;
    int beg = rowptr[v], end = rowptr[v + 1];
    float ad = adst[v];
    float den = 0.f, acc = 0.f;
    int i = beg;
    for (; i + 4 <= end; i += 4) {
        int s0 = col[i], s1 = col[i + 1], s2 = col[i + 2], s3 = col[i + 3];
        float a0 = asrc[s0] + ad;
        float a1 = asrc[s1] + ad;
        float a2 = asrc[s2] + ad;
        float a3 = asrc[s3] + ad;
        float f0 = hfeat[(size_t)s0 * 64 + lane];
        float f1 = hfeat[(size_t)s1 * 64 + lane];
        float f2 = hfeat[(size_t)s2 * 64 + lane];
        float f3 = hfeat[(size_t)s3 * 64 + lane];
        float e0 = __expf(lrelu(a0));
        float e1 = __expf(lrelu(a1));
        float e2 = __expf(lrelu(a2));
        float e3 = __expf(lrelu(a3));
        den += (e0 + e1) + (e2 + e3);
        acc = fmaf(e0, f0, fmaf(e1, f1, fmaf(e2, f2, fmaf(e3, f3, acc))));
    }
    for (; i < end; ++i) {
        int s = col[i];
        float e = __expf(lrelu(asrc[s] + ad));
        den += e;
        acc = fmaf(e, hfeat[(size_t)s * 64 + lane], acc);
    }
    z2[(size_t)v * 64 + lane] = acc / fmaxf(den, 1e-16f) + bias[lane];
}

// logits[i] = dot64(z2[a], z2[b]); 16 lanes per logit, float4 loads
__global__ void logits_kernel(const int* __restrict__ pos, const int* __restrict__ neg,
                              const float* __restrict__ z2, float* __restrict__ out) {
    int t = blockIdx.x * 256 + threadIdx.x;
    int i = t >> 4;
    if (i >= 2 * ETEST) return;
    int sub = t & 15;
    int a, b;
    if (i < ETEST) { a = pos[i]; b = pos[ETEST + i]; }
    else           { a = neg[i - ETEST]; b = neg[i]; }
    float4 va = ((const float4*)(z2 + (size_t)a * 64))[sub];
    float4 vb = ((const float4*)(z2 + (size_t)b * 64))[sub];
    float p = fmaf(va.x, vb.x, fmaf(va.y, vb.y, fmaf(va.z, vb.z, va.w * vb.w)));
#pragma unroll
    for (int off = 8; off >= 1; off >>= 1) p += __shfl_xor(p, off, 64);
    if (sub == 0) out[i] = p;
}

extern "C" void kernel_launch(void* const* d_in, const int* in_sizes, int n_in,
                              void* d_out, int out_size, void* d_ws, size_t ws_size,
                              hipStream_t stream) {
    const float* x    = (const float*)d_in[0];
    const int*   ei   = (const int*)d_in[1];
    const int*   pos  = (const int*)d_in[2];
    const int*   neg  = (const int*)d_in[3];
    const float* W1   = (const float*)d_in[4];
    const float* asr1 = (const float*)d_in[5];
    const float* ads1 = (const float*)d_in[6];
    const float* b1   = (const float*)d_in[7];
    const float* W2   = (const float*)d_in[8];
    const float* asr2 = (const float*)d_in[9];
    const float* ads2 = (const float*)d_in[10];
    const float* b2   = (const float*)d_in[11];
    float* out = (float*)d_out;

    float* ws  = (float*)d_ws;
    float* h1  = ws;                       // NN*64 (h of layer1, reused as h of layer2)
    float* z1  = h1 + (size_t)NN * 64;     // NN*64
    float* z2  = z1 + (size_t)NN * 64;     // NN*64
    float* as1 = z2 + (size_t)NN * 64;     // NN*8
    float* ad1 = as1 + (size_t)NN * 8;     // NN*8
    float* as2 = ad1 + (size_t)NN * 8;     // NN
    float* ad2 = as2 + NN;                 // NN
    int* deg    = (int*)(ad2 + NN);        // NN
    int* rowptr = deg + NN;                // NN+1
    int* cursor = rowptr + NN + 1;         // NN
    int* csrcol = cursor + NN;             // EP

    // ---- CSR build (shared by both layers) ----
    hipMemsetAsync(deg, 0, (size_t)NN * sizeof(int), stream);
    hist_kernel<<<cdiv(EP, 256), 256, 0, stream>>>(ei, deg);
    scan_kernel<<<1, 1024, 0, stream>>>(deg, rowptr, cursor);
    fill_kernel<<<cdiv(EP, 256), 256, 0, stream>>>(ei, cursor, csrcol);

    // ---- layer 1 ----
    gemm1_kernel<<<GB1, 256, 0, stream>>>(x, W1, asr1, ads1, h1, as1, ad1);
    gat1_gather<<<cdiv(NN, 4), 256, 0, stream>>>(rowptr, csrcol, as1, ad1, h1, b1, z1);

    // ---- layer 2 ----
    gemm2_kernel<<<GB1, 256, 0, stream>>>(z1, W2, asr2, ads2, h1, as2, ad2);
    gat2_gather<<<cdiv(NN, 4), 256, 0, stream>>>(rowptr, csrcol, as2, ad2, h1, b2, z2);

    // ---- link-prediction logits ----
    logits_kernel<<<cdiv((long long)2 * ETEST * 16, 256), 256, 0, stream>>>(pos, neg, z2, out);
}

// Round 4
// 410.592 us; speedup vs baseline: 2.1033x; 1.2712x over previous
//
#include <hip/hip_runtime.h>
#include <math.h>

#define NN 50000
#define FIN 128
#define EE 800000
#define EP 850000            // EE + NN self-loops
#define ETEST 100000
#define NEG_SLOPE 0.2f
#define SCAN_B 196           // ceil(NN/256)

static inline int cdiv(long long a, int b) { return (int)((a + b - 1) / b); }

// ---------------- CSR build (by dst), rebuilt every call ----------------

__global__ void hist_kernel(const int* __restrict__ ei, int* __restrict__ deg) {
    int e = blockIdx.x * 256 + threadIdx.x;
    if (e >= EP) return;
    int dst = (e < EE) ? ei[EE + e] : (e - EE);
    atomicAdd(&deg[dst], 1);
}

// two-level scan, step 1: per-block (256-wide) sums of deg
__global__ void block_sums(const int* __restrict__ deg, int* __restrict__ bsum) {
    int idx = blockIdx.x * 256 + threadIdx.x;
    int v = (idx < NN) ? deg[idx] : 0;
#pragma unroll
    for (int off = 32; off >= 1; off >>= 1) v += __shfl_xor(v, off, 64);
    __shared__ int ws[4];
    if ((threadIdx.x & 63) == 0) ws[threadIdx.x >> 6] = v;
    __syncthreads();
    if (threadIdx.x == 0) bsum[blockIdx.x] = ws[0] + ws[1] + ws[2] + ws[3];
}

// step 2: exclusive scan of SCAN_B block sums (single tiny block)
__global__ void scan_bsums(const int* __restrict__ bsum, int* __restrict__ boff,
                           int* __restrict__ rowptr) {
    __shared__ int s[256];
    int t = threadIdx.x;
    int v = (t < SCAN_B) ? bsum[t] : 0;
    s[t] = v;
    __syncthreads();
#pragma unroll
    for (int off = 1; off < 256; off <<= 1) {
        int u = (t >= off) ? s[t - off] : 0;
        __syncthreads();
        s[t] += u;
        __syncthreads();
    }
    if (t < SCAN_B) boff[t] = s[t] - v;   // exclusive
    if (t == 0) rowptr[NN] = EP;
}

// step 3: per-block inclusive scan + offset -> rowptr, cursor
__global__ void scan_final(const int* __restrict__ deg, const int* __restrict__ boff,
                           int* __restrict__ rowptr, int* __restrict__ cursor) {
    __shared__ int s[256];
    int t = threadIdx.x;
    int idx = blockIdx.x * 256 + t;
    int v = (idx < NN) ? deg[idx] : 0;
    s[t] = v;
    __syncthreads();
#pragma unroll
    for (int off = 1; off < 256; off <<= 1) {
        int u = (t >= off) ? s[t - off] : 0;
        __syncthreads();
        s[t] += u;
        __syncthreads();
    }
    if (idx < NN) {
        int excl = boff[blockIdx.x] + s[t] - v;
        rowptr[idx] = excl;
        cursor[idx] = excl;
    }
}

__global__ void fill_kernel(const int* __restrict__ ei, int* __restrict__ cursor,
                            int* __restrict__ col) {
    int e = blockIdx.x * 256 + threadIdx.x;
    if (e >= EP) return;
    int src, dst;
    if (e < EE) { src = ei[e]; dst = ei[EE + e]; } else { src = dst = e - EE; }
    int pos = atomicAdd(&cursor[dst], 1);
    col[pos] = src;
}

// ---------------- GEMMs with fused attention dots (grid-stride rows) ----------------

#define GB1 1250   // blocks for gemm kernels; rows stride = GB1*4 waves

// x[NN,128] @ W[128,64] -> h[NN,64]; per-head dots (H=8,C=8)
__global__ void gemm1_kernel(const float* __restrict__ x, const float* __restrict__ W,
                             const float* __restrict__ att_src, const float* __restrict__ att_dst,
                             float* __restrict__ h, float* __restrict__ a_src, float* __restrict__ a_dst) {
    __shared__ float Ws[FIN * 64];
    int tid = threadIdx.x;
    for (int i = tid; i < FIN * 64; i += 256) Ws[i] = W[i];
    __syncthreads();
    int col = tid & 63;
    int head = col >> 3, c = col & 7;
    float atts = att_src[head * 8 + c];
    float attd = att_dst[head * 8 + c];
    for (int row = blockIdx.x * 4 + (tid >> 6); row < NN; row += GB1 * 4) {
        const float* xr = x + (size_t)row * FIN;
        float acc = 0.f;
#pragma unroll 8
        for (int k = 0; k < FIN; ++k) acc = fmaf(xr[k], Ws[k * 64 + col], acc);
        h[(size_t)row * 64 + col] = acc;
        float ps = acc * atts;
        float pd = acc * attd;
#pragma unroll
        for (int off = 4; off >= 1; off >>= 1) {   // reduce within 8-lane head groups
            ps += __shfl_xor(ps, off, 64);
            pd += __shfl_xor(pd, off, 64);
        }
        if (c == 0) { a_src[row * 8 + head] = ps; a_dst[row * 8 + head] = pd; }
    }
}

// z[NN,64] @ W[64,64] -> h[NN,64]; dots (H=1,C=64)
__global__ void gemm2_kernel(const float* __restrict__ z, const float* __restrict__ W,
                             const float* __restrict__ att_src, const float* __restrict__ att_dst,
                             float* __restrict__ h, float* __restrict__ a_src, float* __restrict__ a_dst) {
    __shared__ float Ws[64 * 64];
    int tid = threadIdx.x;
    for (int i = tid; i < 64 * 64; i += 256) Ws[i] = W[i];
    __syncthreads();
    int col = tid & 63;
    float atts = att_src[col];
    float attd = att_dst[col];
    for (int row = blockIdx.x * 4 + (tid >> 6); row < NN; row += GB1 * 4) {
        const float* zr = z + (size_t)row * 64;
        float acc = 0.f;
#pragma unroll 8
        for (int k = 0; k < 64; ++k) acc = fmaf(zr[k], Ws[k * 64 + col], acc);
        h[(size_t)row * 64 + col] = acc;
        float ps = acc * atts;
        float pd = acc * attd;
#pragma unroll
        for (int off = 32; off >= 1; off >>= 1) {
            ps += __shfl_xor(ps, off, 64);
            pd += __shfl_xor(pd, off, 64);
        }
        if (col == 0) { a_src[row] = ps; a_dst[row] = pd; }
    }
}

// ---------------- Fused GAT aggregation: single pass, no max (cancels), 4x unroll ----------------

__device__ __forceinline__ float lrelu(float a) { return a > 0.f ? a : NEG_SLOPE * a; }

// Layer 1: H=8, C=8. One wave per dst node; lane = h*8+c.
__global__ void gat1_gather(const int* __restrict__ rowptr, const int* __restrict__ col,
                            const float* __restrict__ asrc, const float* __restrict__ adst,
                            const float* __restrict__ hfeat, const float* __restrict__ bias,
                            float* __restrict__ z1) {
    int v = blockIdx.x * 4 + (threadIdx.x >> 6);
    if (v >= NN) return;
    int lane = threadIdx.x & 63;
    int h = lane >> 3;
    int beg = rowptr[v], end = rowptr[v + 1];
    float ad = adst[v * 8 + h];
    float den = 0.f, acc = 0.f;
    int i = beg;
    for (; i + 4 <= end; i += 4) {
        int s0 = col[i], s1 = col[i + 1], s2 = col[i + 2], s3 = col[i + 3];
        float a0 = asrc[s0 * 8 + h] + ad;
        float a1 = asrc[s1 * 8 + h] + ad;
        float a2 = asrc[s2 * 8 + h] + ad;
        float a3 = asrc[s3 * 8 + h] + ad;
        float f0 = hfeat[(size_t)s0 * 64 + lane];
        float f1 = hfeat[(size_t)s1 * 64 + lane];
        float f2 = hfeat[(size_t)s2 * 64 + lane];
        float f3 = hfeat[(size_t)s3 * 64 + lane];
        float e0 = __expf(lrelu(a0));
        float e1 = __expf(lrelu(a1));
        float e2 = __expf(lrelu(a2));
        float e3 = __expf(lrelu(a3));
        den += (e0 + e1) + (e2 + e3);
        acc = fmaf(e0, f0, fmaf(e1, f1, fmaf(e2, f2, fmaf(e3, f3, acc))));
    }
    for (; i < end; ++i) {
        int s = col[i];
        float e = __expf(lrelu(asrc[s * 8 + h] + ad));
        den += e;
        acc = fmaf(e, hfeat[(size_t)s * 64 + lane], acc);
    }
    float o = acc / fmaxf(den, 1e-16f) + bias[lane];
    z1[(size_t)v * 64 + lane] = o > 0.f ? o : expm1f(o);   // fused ELU
}

// Layer 2: H=1, C=64.
__global__ void gat2_gather(const int* __restrict__ rowptr, const int* __restrict__ col,
                            const float* __restrict__ asrc, const float* __restrict__ adst,
                            const float* __restrict__ hfeat, const float* __restrict__ bias,
                            float* __restrict__ z2) {
    int v = blockIdx.x * 4 + (threadIdx.x >> 6);
    if (v >= NN) return;
    int lane = threadIdx.x & 63;
    int beg = rowptr[v], end = rowptr[v + 1];
    float ad = adst[v];
    float den = 0.f, acc = 0.f;
    int i = beg;
    for (; i + 4 <= end; i += 4) {
        int s0 = col[i], s1 = col[i + 1], s2 = col[i + 2], s3 = col[i + 3];
        float a0 = asrc[s0] + ad;
        float a1 = asrc[s1] + ad;
        float a2 = asrc[s2] + ad;
        float a3 = asrc[s3] + ad;
        float f0 = hfeat[(size_t)s0 * 64 + lane];
        float f1 = hfeat[(size_t)s1 * 64 + lane];
        float f2 = hfeat[(size_t)s2 * 64 + lane];
        float f3 = hfeat[(size_t)s3 * 64 + lane];
        float e0 = __expf(lrelu(a0));
        float e1 = __expf(lrelu(a1));
        float e2 = __expf(lrelu(a2));
        float e3 = __expf(lrelu(a3));
        den += (e0 + e1) + (e2 + e3);
        acc = fmaf(e0, f0, fmaf(e1, f1, fmaf(e2, f2, fmaf(e3, f3, acc))));
    }
    for (; i < end; ++i) {
        int s = col[i];
        float e = __expf(lrelu(asrc[s] + ad));
        den += e;
        acc = fmaf(e, hfeat[(size_t)s * 64 + lane], acc);
    }
    z2[(size_t)v * 64 + lane] = acc / fmaxf(den, 1e-16f) + bias[lane];
}

// logits[i] = dot64(z2[a], z2[b]); 16 lanes per logit, float4 loads
__global__ void logits_kernel(const int* __restrict__ pos, const int* __restrict__ neg,
                              const float* __restrict__ z2, float* __restrict__ out) {
    int t = blockIdx.x * 256 + threadIdx.x;
    int i = t >> 4;
    if (i >= 2 * ETEST) return;
    int sub = t & 15;
    int a, b;
    if (i < ETEST) { a = pos[i]; b = pos[ETEST + i]; }
    else           { a = neg[i - ETEST]; b = neg[i]; }
    float4 va = ((const float4*)(z2 + (size_t)a * 64))[sub];
    float4 vb = ((const float4*)(z2 + (size_t)b * 64))[sub];
    float p = fmaf(va.x, vb.x, fmaf(va.y, vb.y, fmaf(va.z, vb.z, va.w * vb.w)));
#pragma unroll
    for (int off = 8; off >= 1; off >>= 1) p += __shfl_xor(p, off, 64);
    if (sub == 0) out[i] = p;
}

extern "C" void kernel_launch(void* const* d_in, const int* in_sizes, int n_in,
                              void* d_out, int out_size, void* d_ws, size_t ws_size,
                              hipStream_t stream) {
    const float* x    = (const float*)d_in[0];
    const int*   ei   = (const int*)d_in[1];
    const int*   pos  = (const int*)d_in[2];
    const int*   neg  = (const int*)d_in[3];
    const float* W1   = (const float*)d_in[4];
    const float* asr1 = (const float*)d_in[5];
    const float* ads1 = (const float*)d_in[6];
    const float* b1   = (const float*)d_in[7];
    const float* W2   = (const float*)d_in[8];
    const float* asr2 = (const float*)d_in[9];
    const float* ads2 = (const float*)d_in[10];
    const float* b2   = (const float*)d_in[11];
    float* out = (float*)d_out;

    float* ws  = (float*)d_ws;
    float* h1  = ws;                       // NN*64 (h of layer1, reused as h of layer2)
    float* z1  = h1 + (size_t)NN * 64;     // NN*64
    float* z2  = z1 + (size_t)NN * 64;     // NN*64
    float* as1 = z2 + (size_t)NN * 64;     // NN*8
    float* ad1 = as1 + (size_t)NN * 8;     // NN*8
    float* as2 = ad1 + (size_t)NN * 8;     // NN
    float* ad2 = as2 + NN;                 // NN
    int* deg    = (int*)(ad2 + NN);        // NN
    int* rowptr = deg + NN;                // NN+1
    int* cursor = rowptr + NN + 1;         // NN
    int* bsum   = cursor + NN;             // SCAN_B
    int* boff   = bsum + SCAN_B;           // SCAN_B
    int* csrcol = boff + SCAN_B;           // EP

    // ---- CSR build (shared by both layers) ----
    hipMemsetAsync(deg, 0, (size_t)NN * sizeof(int), stream);
    hist_kernel<<<cdiv(EP, 256), 256, 0, stream>>>(ei, deg);
    block_sums<<<SCAN_B, 256, 0, stream>>>(deg, bsum);
    scan_bsums<<<1, 256, 0, stream>>>(bsum, boff, rowptr);
    scan_final<<<SCAN_B, 256, 0, stream>>>(deg, boff, rowptr, cursor);
    fill_kernel<<<cdiv(EP, 256), 256, 0, stream>>>(ei, cursor, csrcol);

    // ---- layer 1 ----
    gemm1_kernel<<<GB1, 256, 0, stream>>>(x, W1, asr1, ads1, h1, as1, ad1);
    gat1_gather<<<cdiv(NN, 4), 256, 0, stream>>>(rowptr, csrcol, as1, ad1, h1, b1, z1);

    // ---- layer 2 ----
    gemm2_kernel<<<GB1, 256, 0, stream>>>(z1, W2, asr2, ads2, h1, as2, ad2);
    gat2_gather<<<cdiv(NN, 4), 256, 0, stream>>>(rowptr, csrcol, as2, ad2, h1, b2, z2);

    // ---- link-prediction logits ----
    logits_kernel<<<cdiv((long long)2 * ETEST * 16, 256), 256, 0, stream>>>(pos, neg, z2, out);
}

// Round 5
// 326.379 us; speedup vs baseline: 2.6460x; 1.2580x over previous
//
#include <hip/hip_runtime.h>
#include <math.h>

#define NN 50000
#define FIN 128
#define EE 800000
#define EP 850000            // EE + NN self-loops
#define ETEST 100000
#define NEG_SLOPE 0.2f
#define SCAN_B 196           // ceil(NN/256)
#define XP 68                // LDS pitch for transposed x tile (16B-aligned quads)

static inline int cdiv(long long a, int b) { return (int)((a + b - 1) / b); }

// ---------------- CSR build (by dst), rebuilt every call ----------------

__global__ void hist_kernel(const int* __restrict__ ei, int* __restrict__ deg) {
    int e = blockIdx.x * 256 + threadIdx.x;
    if (e >= EP) return;
    int dst = (e < EE) ? ei[EE + e] : (e - EE);
    atomicAdd(&deg[dst], 1);
}

__global__ void block_sums(const int* __restrict__ deg, int* __restrict__ bsum) {
    int idx = blockIdx.x * 256 + threadIdx.x;
    int v = (idx < NN) ? deg[idx] : 0;
#pragma unroll
    for (int off = 32; off >= 1; off >>= 1) v += __shfl_xor(v, off, 64);
    __shared__ int ws[4];
    if ((threadIdx.x & 63) == 0) ws[threadIdx.x >> 6] = v;
    __syncthreads();
    if (threadIdx.x == 0) bsum[blockIdx.x] = ws[0] + ws[1] + ws[2] + ws[3];
}

__global__ void scan_bsums(const int* __restrict__ bsum, int* __restrict__ boff,
                           int* __restrict__ rowptr) {
    __shared__ int s[256];
    int t = threadIdx.x;
    int v = (t < SCAN_B) ? bsum[t] : 0;
    s[t] = v;
    __syncthreads();
#pragma unroll
    for (int off = 1; off < 256; off <<= 1) {
        int u = (t >= off) ? s[t - off] : 0;
        __syncthreads();
        s[t] += u;
        __syncthreads();
    }
    if (t < SCAN_B) boff[t] = s[t] - v;   // exclusive
    if (t == 0) rowptr[NN] = EP;
}

__global__ void scan_final(const int* __restrict__ deg, const int* __restrict__ boff,
                           int* __restrict__ rowptr, int* __restrict__ cursor) {
    __shared__ int s[256];
    int t = threadIdx.x;
    int idx = blockIdx.x * 256 + t;
    int v = (idx < NN) ? deg[idx] : 0;
    s[t] = v;
    __syncthreads();
#pragma unroll
    for (int off = 1; off < 256; off <<= 1) {
        int u = (t >= off) ? s[t - off] : 0;
        __syncthreads();
        s[t] += u;
        __syncthreads();
    }
    if (idx < NN) {
        int excl = boff[blockIdx.x] + s[t] - v;
        rowptr[idx] = excl;
        cursor[idx] = excl;
    }
}

__global__ void fill_kernel(const int* __restrict__ ei, int* __restrict__ cursor,
                            int* __restrict__ col) {
    int e = blockIdx.x * 256 + threadIdx.x;
    if (e >= EP) return;
    int src, dst;
    if (e < EE) { src = ei[e]; dst = ei[EE + e]; } else { src = dst = e - EE; }
    int pos = atomicAdd(&cursor[dst], 1);
    col[pos] = src;
}

// ---------------- Register-tiled GEMMs (64x64 tile, 4x4 acc per lane) ----------------
// Lane map: wave w (4/block), lane l: rg=l>>4 (4 row groups), cg=l&15 (16 col groups).
// Lane owns rows B+16w+4rg+{0..3}, cols 4cg+{0..3}.

// x[NN,128] @ W[128,64] -> h; fused per-head dots (H=8,C=8)
__global__ void __launch_bounds__(256) gemm1_kernel(
        const float* __restrict__ x, const float* __restrict__ W,
        const float* __restrict__ att_src, const float* __restrict__ att_dst,
        float* __restrict__ h, float* __restrict__ a_src, float* __restrict__ a_dst) {
    __shared__ __align__(16) float Ws[FIN * 64];     // 32 KB
    __shared__ __align__(16) float xs[32 * XP];      // 8.7 KB, transposed chunk [k][r]
    int tid = threadIdx.x;
    for (int i = tid; i < FIN * 64 / 4; i += 256)
        ((float4*)Ws)[i] = ((const float4*)W)[i];
    int B = blockIdx.x * 64;
    int wave = tid >> 6, lane = tid & 63;
    int rg = lane >> 4, cg = lane & 15;
    int rbase = wave * 16 + rg * 4;
    float acc[4][4] = {};
    for (int kc = 0; kc < FIN; kc += 32) {
        __syncthreads();
        // stage x[B..B+63][kc..kc+31] -> xs[k][r], 512 float4 loads
#pragma unroll
        for (int p = 0; p < 2; ++p) {
            int idx = p * 256 + tid;            // 0..511
            int r = idx >> 3;                   // 0..63
            int m = idx & 7;                    // float4 within 32 cols
            int row = B + r;
            float4 v = (row < NN) ? ((const float4*)(x + (size_t)row * FIN + kc))[m]
                                  : make_float4(0.f, 0.f, 0.f, 0.f);
            int c4 = m << 2;
            xs[(c4 + 0) * XP + r] = v.x;
            xs[(c4 + 1) * XP + r] = v.y;
            xs[(c4 + 2) * XP + r] = v.z;
            xs[(c4 + 3) * XP + r] = v.w;
        }
        __syncthreads();
#pragma unroll 4
        for (int k = 0; k < 32; ++k) {
            float4 w4 = *(const float4*)&Ws[(kc + k) * 64 + cg * 4];
            float4 x4 = *(const float4*)&xs[k * XP + rbase];
            acc[0][0] = fmaf(x4.x, w4.x, acc[0][0]); acc[0][1] = fmaf(x4.x, w4.y, acc[0][1]);
            acc[0][2] = fmaf(x4.x, w4.z, acc[0][2]); acc[0][3] = fmaf(x4.x, w4.w, acc[0][3]);
            acc[1][0] = fmaf(x4.y, w4.x, acc[1][0]); acc[1][1] = fmaf(x4.y, w4.y, acc[1][1]);
            acc[1][2] = fmaf(x4.y, w4.z, acc[1][2]); acc[1][3] = fmaf(x4.y, w4.w, acc[1][3]);
            acc[2][0] = fmaf(x4.z, w4.x, acc[2][0]); acc[2][1] = fmaf(x4.z, w4.y, acc[2][1]);
            acc[2][2] = fmaf(x4.z, w4.z, acc[2][2]); acc[2][3] = fmaf(x4.z, w4.w, acc[2][3]);
            acc[3][0] = fmaf(x4.w, w4.x, acc[3][0]); acc[3][1] = fmaf(x4.w, w4.y, acc[3][1]);
            acc[3][2] = fmaf(x4.w, w4.z, acc[3][2]); acc[3][3] = fmaf(x4.w, w4.w, acc[3][3]);
        }
    }
    // epilogue: h store + per-head attention dots (head = cg>>1; flat att idx = 4cg+i)
    float as0 = att_src[4 * cg + 0], as1 = att_src[4 * cg + 1],
          as2 = att_src[4 * cg + 2], as3 = att_src[4 * cg + 3];
    float ad0 = att_dst[4 * cg + 0], ad1 = att_dst[4 * cg + 1],
          ad2 = att_dst[4 * cg + 2], ad3 = att_dst[4 * cg + 3];
#pragma unroll
    for (int j = 0; j < 4; ++j) {
        int row = B + rbase + j;
        if (row >= NN) continue;
        float4 hv = make_float4(acc[j][0], acc[j][1], acc[j][2], acc[j][3]);
        *(float4*)(h + (size_t)row * 64 + cg * 4) = hv;
        float ps = fmaf(hv.x, as0, fmaf(hv.y, as1, fmaf(hv.z, as2, hv.w * as3)));
        float pd = fmaf(hv.x, ad0, fmaf(hv.y, ad1, fmaf(hv.z, ad2, hv.w * ad3)));
        ps += __shfl_xor(ps, 1, 64);
        pd += __shfl_xor(pd, 1, 64);
        if ((cg & 1) == 0) {
            a_src[row * 8 + (cg >> 1)] = ps;
            a_dst[row * 8 + (cg >> 1)] = pd;
        }
    }
}

// z[NN,64] @ W[64,64] -> h; fused dots (H=1,C=64)
__global__ void __launch_bounds__(256) gemm2_kernel(
        const float* __restrict__ z, const float* __restrict__ W,
        const float* __restrict__ att_src, const float* __restrict__ att_dst,
        float* __restrict__ h, float* __restrict__ a_src, float* __restrict__ a_dst) {
    __shared__ __align__(16) float Ws[64 * 64];      // 16 KB
    __shared__ __align__(16) float xs[64 * XP];      // 17.4 KB, transposed [k][r]
    int tid = threadIdx.x;
    for (int i = tid; i < 64 * 64 / 4; i += 256)
        ((float4*)Ws)[i] = ((const float4*)W)[i];
    int B = blockIdx.x * 64;
#pragma unroll
    for (int p = 0; p < 4; ++p) {
        int idx = p * 256 + tid;                // 0..1023
        int r = idx >> 4;                       // 0..63
        int m = idx & 15;
        int row = B + r;
        float4 v = (row < NN) ? ((const float4*)(z + (size_t)row * 64))[m]
                              : make_float4(0.f, 0.f, 0.f, 0.f);
        int c4 = m << 2;
        xs[(c4 + 0) * XP + r] = v.x;
        xs[(c4 + 1) * XP + r] = v.y;
        xs[(c4 + 2) * XP + r] = v.z;
        xs[(c4 + 3) * XP + r] = v.w;
    }
    int wave = tid >> 6, lane = tid & 63;
    int rg = lane >> 4, cg = lane & 15;
    int rbase = wave * 16 + rg * 4;
    float acc[4][4] = {};
    __syncthreads();
#pragma unroll 4
    for (int k = 0; k < 64; ++k) {
        float4 w4 = *(const float4*)&Ws[k * 64 + cg * 4];
        float4 x4 = *(const float4*)&xs[k * XP + rbase];
        acc[0][0] = fmaf(x4.x, w4.x, acc[0][0]); acc[0][1] = fmaf(x4.x, w4.y, acc[0][1]);
        acc[0][2] = fmaf(x4.x, w4.z, acc[0][2]); acc[0][3] = fmaf(x4.x, w4.w, acc[0][3]);
        acc[1][0] = fmaf(x4.y, w4.x, acc[1][0]); acc[1][1] = fmaf(x4.y, w4.y, acc[1][1]);
        acc[1][2] = fmaf(x4.y, w4.z, acc[1][2]); acc[1][3] = fmaf(x4.y, w4.w, acc[1][3]);
        acc[2][0] = fmaf(x4.z, w4.x, acc[2][0]); acc[2][1] = fmaf(x4.z, w4.y, acc[2][1]);
        acc[2][2] = fmaf(x4.z, w4.z, acc[2][2]); acc[2][3] = fmaf(x4.z, w4.w, acc[2][3]);
        acc[3][0] = fmaf(x4.w, w4.x, acc[3][0]); acc[3][1] = fmaf(x4.w, w4.y, acc[3][1]);
        acc[3][2] = fmaf(x4.w, w4.z, acc[3][2]); acc[3][3] = fmaf(x4.w, w4.w, acc[3][3]);
    }
    float as0 = att_src[4 * cg + 0], as1 = att_src[4 * cg + 1],
          as2 = att_src[4 * cg + 2], as3 = att_src[4 * cg + 3];
    float ad0 = att_dst[4 * cg + 0], ad1 = att_dst[4 * cg + 1],
          ad2 = att_dst[4 * cg + 2], ad3 = att_dst[4 * cg + 3];
#pragma unroll
    for (int j = 0; j < 4; ++j) {
        int row = B + rbase + j;
        if (row >= NN) continue;
        float4 hv = make_float4(acc[j][0], acc[j][1], acc[j][2], acc[j][3]);
        *(float4*)(h + (size_t)row * 64 + cg * 4) = hv;
        float ps = fmaf(hv.x, as0, fmaf(hv.y, as1, fmaf(hv.z, as2, hv.w * as3)));
        float pd = fmaf(hv.x, ad0, fmaf(hv.y, ad1, fmaf(hv.z, ad2, hv.w * ad3)));
#pragma unroll
        for (int off = 8; off >= 1; off >>= 1) {   // reduce across 16 cgs
            ps += __shfl_xor(ps, off, 64);
            pd += __shfl_xor(pd, off, 64);
        }
        if (cg == 0) { a_src[row] = ps; a_dst[row] = pd; }
    }
}

// ---------------- Fused GAT aggregation: single pass, no max (cancels), 8x unroll ----------------

__device__ __forceinline__ float lrelu(float a) { return a > 0.f ? a : NEG_SLOPE * a; }

__global__ void gat1_gather(const int* __restrict__ rowptr, const int* __restrict__ col,
                            const float* __restrict__ asrc, const float* __restrict__ adst,
                            const float* __restrict__ hfeat, const float* __restrict__ bias,
                            float* __restrict__ z1) {
    int v = blockIdx.x * 4 + (threadIdx.x >> 6);
    if (v >= NN) return;
    int lane = threadIdx.x & 63;
    int h = lane >> 3;
    int beg = rowptr[v], end = rowptr[v + 1];
    float ad = adst[v * 8 + h];
    float den = 0.f, acc = 0.f;
    int i = beg;
    for (; i + 8 <= end; i += 8) {
        int s[8]; float a[8], f[8];
#pragma unroll
        for (int u = 0; u < 8; ++u) s[u] = col[i + u];
#pragma unroll
        for (int u = 0; u < 8; ++u) a[u] = asrc[s[u] * 8 + h] + ad;
#pragma unroll
        for (int u = 0; u < 8; ++u) f[u] = hfeat[(size_t)s[u] * 64 + lane];
#pragma unroll
        for (int u = 0; u < 8; ++u) {
            float e = __expf(lrelu(a[u]));
            den += e;
            acc = fmaf(e, f[u], acc);
        }
    }
    for (; i < end; ++i) {
        int s = col[i];
        float e = __expf(lrelu(asrc[s * 8 + h] + ad));
        den += e;
        acc = fmaf(e, hfeat[(size_t)s * 64 + lane], acc);
    }
    float o = acc / fmaxf(den, 1e-16f) + bias[lane];
    z1[(size_t)v * 64 + lane] = o > 0.f ? o : expm1f(o);   // fused ELU
}

__global__ void gat2_gather(const int* __restrict__ rowptr, const int* __restrict__ col,
                            const float* __restrict__ asrc, const float* __restrict__ adst,
                            const float* __restrict__ hfeat, const float* __restrict__ bias,
                            float* __restrict__ z2) {
    int v = blockIdx.x * 4 + (threadIdx.x >> 6);
    if (v >= NN) return;
    int lane = threadIdx.x & 63;
    int beg = rowptr[v], end = rowptr[v + 1];
    float ad = adst[v];
    float den = 0.f, acc = 0.f;
    int i = beg;
    for (; i + 8 <= end; i += 8) {
        int s[8]; float a[8], f[8];
#pragma unroll
        for (int u = 0; u < 8; ++u) s[u] = col[i + u];
#pragma unroll
        for (int u = 0; u < 8; ++u) a[u] = asrc[s[u]] + ad;
#pragma unroll
        for (int u = 0; u < 8; ++u) f[u] = hfeat[(size_t)s[u] * 64 + lane];
#pragma unroll
        for (int u = 0; u < 8; ++u) {
            float e = __expf(lrelu(a[u]));
            den += e;
            acc = fmaf(e, f[u], acc);
        }
    }
    for (; i < end; ++i) {
        int s = col[i];
        float e = __expf(lrelu(asrc[s] + ad));
        den += e;
        acc = fmaf(e, hfeat[(size_t)s * 64 + lane], acc);
    }
    z2[(size_t)v * 64 + lane] = acc / fmaxf(den, 1e-16f) + bias[lane];
}

// logits[i] = dot64(z2[a], z2[b]); 16 lanes per logit, float4 loads
__global__ void logits_kernel(const int* __restrict__ pos, const int* __restrict__ neg,
                              const float* __restrict__ z2, float* __restrict__ out) {
    int t = blockIdx.x * 256 + threadIdx.x;
    int i = t >> 4;
    if (i >= 2 * ETEST) return;
    int sub = t & 15;
    int a, b;
    if (i < ETEST) { a = pos[i]; b = pos[ETEST + i]; }
    else           { a = neg[i - ETEST]; b = neg[i]; }
    float4 va = ((const float4*)(z2 + (size_t)a * 64))[sub];
    float4 vb = ((const float4*)(z2 + (size_t)b * 64))[sub];
    float p = fmaf(va.x, vb.x, fmaf(va.y, vb.y, fmaf(va.z, vb.z, va.w * vb.w)));
#pragma unroll
    for (int off = 8; off >= 1; off >>= 1) p += __shfl_xor(p, off, 64);
    if (sub == 0) out[i] = p;
}

extern "C" void kernel_launch(void* const* d_in, const int* in_sizes, int n_in,
                              void* d_out, int out_size, void* d_ws, size_t ws_size,
                              hipStream_t stream) {
    const float* x    = (const float*)d_in[0];
    const int*   ei   = (const int*)d_in[1];
    const int*   pos  = (const int*)d_in[2];
    const int*   neg  = (const int*)d_in[3];
    const float* W1   = (const float*)d_in[4];
    const float* asr1 = (const float*)d_in[5];
    const float* ads1 = (const float*)d_in[6];
    const float* b1   = (const float*)d_in[7];
    const float* W2   = (const float*)d_in[8];
    const float* asr2 = (const float*)d_in[9];
    const float* ads2 = (const float*)d_in[10];
    const float* b2   = (const float*)d_in[11];
    float* out = (float*)d_out;

    float* ws  = (float*)d_ws;
    float* h1  = ws;                       // NN*64 (h of layer1, reused as h of layer2)
    float* z1  = h1 + (size_t)NN * 64;     // NN*64
    float* z2  = z1 + (size_t)NN * 64;     // NN*64
    float* as1 = z2 + (size_t)NN * 64;     // NN*8
    float* ad1 = as1 + (size_t)NN * 8;     // NN*8
    float* as2 = ad1 + (size_t)NN * 8;     // NN
    float* ad2 = as2 + NN;                 // NN
    int* deg    = (int*)(ad2 + NN);        // NN
    int* rowptr = deg + NN;                // NN+1
    int* cursor = rowptr + NN + 1;         // NN
    int* bsum   = cursor + NN;             // SCAN_B
    int* boff   = bsum + SCAN_B;           // SCAN_B
    int* csrcol = boff + SCAN_B;           // EP

    // ---- CSR build (shared by both layers) ----
    hipMemsetAsync(deg, 0, (size_t)NN * sizeof(int), stream);
    hist_kernel<<<cdiv(EP, 256), 256, 0, stream>>>(ei, deg);
    block_sums<<<SCAN_B, 256, 0, stream>>>(deg, bsum);
    scan_bsums<<<1, 256, 0, stream>>>(bsum, boff, rowptr);
    scan_final<<<SCAN_B, 256, 0, stream>>>(deg, boff, rowptr, cursor);
    fill_kernel<<<cdiv(EP, 256), 256, 0, stream>>>(ei, cursor, csrcol);

    // ---- layer 1 ----
    gemm1_kernel<<<cdiv(NN, 64), 256, 0, stream>>>(x, W1, asr1, ads1, h1, as1, ad1);
    gat1_gather<<<cdiv(NN, 4), 256, 0, stream>>>(rowptr, csrcol, as1, ad1, h1, b1, z1);

    // ---- layer 2 ----
    gemm2_kernel<<<cdiv(NN, 64), 256, 0, stream>>>(z1, W2, asr2, ads2, h1, as2, ad2);
    gat2_gather<<<cdiv(NN, 4), 256, 0, stream>>>(rowptr, csrcol, as2, ad2, h1, b2, z2);

    // ---- link-prediction logits ----
    logits_kernel<<<cdiv((long long)2 * ETEST * 16, 256), 256, 0, stream>>>(pos, neg, z2, out);
}